// Round 4
// baseline (866.915 us; speedup 1.0000x reference)
//
#include <hip/hip_runtime.h>
#include <hip/hip_bf16.h>
#include <math.h>

#define F_IN 512
#define H_DIM 50
#define C_DIM 40

typedef __bf16 bf16x8 __attribute__((ext_vector_type(8)));
typedef __bf16 bf16x4 __attribute__((ext_vector_type(4)));
typedef float f32x4 __attribute__((ext_vector_type(4)));

// ---------------- CSR build: count -> scan -> fill (single scatter pass) --------

__global__ void zero_int_kernel(int* __restrict__ p, int n) {
    int i = blockIdx.x * blockDim.x + threadIdx.x;
    if (i < n) p[i] = 0;
}

__global__ void count_kernel(const int* __restrict__ dst, int* __restrict__ cnt, int E) {
    int e0 = (blockIdx.x * blockDim.x + threadIdx.x) * 4;
    if (e0 >= E) return;
    if (e0 + 3 < E) {
        int4 d4 = *(const int4*)(dst + e0);
        atomicAdd(&cnt[d4.x], 1);
        atomicAdd(&cnt[d4.y], 1);
        atomicAdd(&cnt[d4.z], 1);
        atomicAdd(&cnt[d4.w], 1);
    } else {
        for (int j = 0; j < 4 && e0 + j < E; ++j) atomicAdd(&cnt[dst[e0 + j]], 1);
    }
}

// scan1: per-block (1024 elems) exclusive scan of cnt -> rowptr (local), blksum[b]
__global__ __launch_bounds__(256) void scan1_kernel(
    const int* __restrict__ cnt, int* __restrict__ rowptr,
    int* __restrict__ blksum, int N) {
    __shared__ int wsum[4];
    const int t = threadIdx.x, lane = t & 63, wv = t >> 6;
    const int base = blockIdx.x * 1024 + t * 4;
    int v[4];
    #pragma unroll
    for (int j = 0; j < 4; ++j) v[j] = (base + j < N) ? cnt[base + j] : 0;
    int tsum = v[0] + v[1] + v[2] + v[3];
    int incl = tsum;
    #pragma unroll
    for (int off = 1; off < 64; off <<= 1) {
        int u = __shfl_up(incl, off, 64);
        if (lane >= off) incl += u;
    }
    if (lane == 63) wsum[wv] = incl;
    __syncthreads();
    int woff = 0;
    #pragma unroll
    for (int w = 0; w < 3; ++w) woff += (w < wv) ? wsum[w] : 0;
    int e = woff + incl - tsum;     // exclusive prefix of this thread's first elem
    #pragma unroll
    for (int j = 0; j < 4; ++j) {
        if (base + j < N) rowptr[base + j] = e;
        e += v[j];
    }
    if (t == 255) blksum[blockIdx.x] = woff + incl;   // block total
}

// scan2: exclusive scan of block sums in place (1 block, 64 threads)
__global__ void scan2_kernel(int* __restrict__ blksum, int nb) {
    const int lane = threadIdx.x;
    int run = 0;
    for (int base = 0; base < nb; base += 64) {
        int v = (base + lane < nb) ? blksum[base + lane] : 0;
        int incl = v;
        #pragma unroll
        for (int off = 1; off < 64; off <<= 1) {
            int u = __shfl_up(incl, off, 64);
            if (lane >= off) incl += u;
        }
        if (base + lane < nb) blksum[base + lane] = run + incl - v;
        run += __shfl(incl, 63, 64);
    }
}

// scan3: add block offsets, init cursor, compute dinv (fused small pass)
__global__ __launch_bounds__(256) void scan3_kernel(
    int* __restrict__ rowptr, const int* __restrict__ blksum,
    int* __restrict__ cursor, const int* __restrict__ cnt,
    float* __restrict__ dinv, int N) {
    const int base = blockIdx.x * 1024 + threadIdx.x * 4;
    const int off = blksum[blockIdx.x];
    #pragma unroll
    for (int j = 0; j < 4; ++j) {
        int i = base + j;
        if (i < N) {
            int r = rowptr[i] + off;
            rowptr[i] = r;
            cursor[i] = r;
            dinv[i] = rsqrtf((float)(cnt[i] + 1));   // +1 self-loop
        }
    }
}

__global__ void csr_fill_kernel(const int* __restrict__ src, const int* __restrict__ dst,
                                int* __restrict__ cursor, int* __restrict__ adj, int E) {
    int e0 = (blockIdx.x * blockDim.x + threadIdx.x) * 4;
    if (e0 >= E) return;
    if (e0 + 3 < E) {
        int4 d4 = *(const int4*)(dst + e0);
        int4 s4 = *(const int4*)(src + e0);
        int dd[4] = {d4.x, d4.y, d4.z, d4.w};
        int ss[4] = {s4.x, s4.y, s4.z, s4.w};
        #pragma unroll
        for (int j = 0; j < 4; ++j) {
            int pos = atomicAdd(&cursor[dd[j]], 1);
            adj[pos] = ss[j];
        }
    } else {
        for (int j = 0; j < 4 && e0 + j < E; ++j) {
            int pos = atomicAdd(&cursor[dst[e0 + j]], 1);
            adj[pos] = src[e0 + j];
        }
    }
}

// ---------------- W1 -> bf16 transposed [64][512] (cols>=50 zero) ----------------

__global__ void prep_wt_kernel(const float* __restrict__ W1, __bf16* __restrict__ wt) {
    int i = blockIdx.x * 256 + threadIdx.x;   // 0..32767
    int n = i >> 9, k = i & 511;
    wt[n * 512 + k] = (n < H_DIM) ? (__bf16)W1[k * H_DIM + n] : (__bf16)0.0f;
}

// ---------------- GEMM1 (MFMA): h1b = bf16( (x @ W1) * dinv[row] ), [N][64] ------
// 128x64 tile, BK=32, 4 waves, double-buffered.
// LDS rows padded to 80 B (40 bf16): frag-read bank-unit = (5*row + q) mod 8 is
// uniform 8 lanes/unit -> conflict-free. 30 KB LDS -> 5 blocks/CU = 62.5% occ.

#define G1_BM 128
#define G1_BK 32
#define A_LDW 40   // padded row stride in bf16 (80 B)

__device__ __forceinline__ bf16x4 pack4(float4 a) {
    bf16x4 r;
    r[0] = (__bf16)a.x; r[1] = (__bf16)a.y; r[2] = (__bf16)a.z; r[3] = (__bf16)a.w;
    return r;
}

__global__ __launch_bounds__(256) void gemm1_mfma_kernel(
    const float* __restrict__ x, const __bf16* __restrict__ wt,
    const float* __restrict__ dinv, __bf16* __restrict__ h1b, int N) {
    __shared__ __bf16 As[2][G1_BM * A_LDW];   // 2 x 10 KB
    __shared__ __bf16 Bs[2][64 * A_LDW];      // 2 x 5 KB

    const int t = threadIdx.x;
    const int wv = t >> 6, ln = t & 63;
    const int q = ln >> 4, l16 = ln & 15;
    const int row0 = blockIdx.x * G1_BM;

    f32x4 acc[2][4];
    #pragma unroll
    for (int a = 0; a < 2; ++a)
        #pragma unroll
        for (int b = 0; b < 4; ++b) acc[a][b] = (f32x4){0.f, 0.f, 0.f, 0.f};

    // A staging: thread owns float4-slot c4 (16 B) of rows r0+32j.
    const int c4 = t & 7;
    const int r0 = t >> 3;          // 0..31
    const float* xp[4];
    #pragma unroll
    for (int j = 0; j < 4; ++j) {
        int gr = row0 + r0 + 32 * j;
        int rc = (gr < N) ? gr : (N - 1);   // clamp: junk A-rows -> discarded C-rows
        xp[j] = x + (long)rc * F_IN + c4 * 4;
    }

    // B staging: thread owns bf16x8 chunk bc of row bn.
    const int bc = t & 3;
    const int bn = t >> 2;          // 0..63
    const __bf16* wb = wt + bn * 512 + bc * 8;

    float4 xv[4];
    uint4 w8;

    #pragma unroll
    for (int j = 0; j < 4; ++j) xv[j] = *(const float4*)(xp[j]);
    w8 = *(const uint4*)(wb);
    #pragma unroll
    for (int j = 0; j < 4; ++j)
        *(bf16x4*)&As[0][(r0 + 32 * j) * A_LDW + c4 * 4] = pack4(xv[j]);
    *(bf16x8*)&Bs[0][bn * A_LDW + bc * 8] = *(bf16x8*)&w8;
    __syncthreads();

    #pragma unroll 1
    for (int tt = 0; tt < F_IN / G1_BK; ++tt) {
        int b = tt & 1;
        if (tt < F_IN / G1_BK - 1) {
            #pragma unroll
            for (int j = 0; j < 4; ++j)
                xv[j] = *(const float4*)(xp[j] + (tt + 1) * G1_BK);
            w8 = *(const uint4*)(wb + (tt + 1) * G1_BK);
        }
        bf16x8 af[2], bfr[4];
        #pragma unroll
        for (int mt = 0; mt < 2; ++mt)
            af[mt] = *(const bf16x8*)&As[b][(wv * 32 + mt * 16 + l16) * A_LDW + q * 8];
        #pragma unroll
        for (int nt = 0; nt < 4; ++nt)
            bfr[nt] = *(const bf16x8*)&Bs[b][(nt * 16 + l16) * A_LDW + q * 8];
        #pragma unroll
        for (int mt = 0; mt < 2; ++mt)
            #pragma unroll
            for (int nt = 0; nt < 4; ++nt)
                acc[mt][nt] = __builtin_amdgcn_mfma_f32_16x16x32_bf16(
                    af[mt], bfr[nt], acc[mt][nt], 0, 0, 0);
        if (tt < F_IN / G1_BK - 1) {
            int nb = b ^ 1;
            #pragma unroll
            for (int j = 0; j < 4; ++j)
                *(bf16x4*)&As[nb][(r0 + 32 * j) * A_LDW + c4 * 4] = pack4(xv[j]);
            *(bf16x8*)&Bs[nb][bn * A_LDW + bc * 8] = *(bf16x8*)&w8;
        }
        __syncthreads();
    }

    #pragma unroll
    for (int mt = 0; mt < 2; ++mt) {
        int rbase = row0 + wv * 32 + mt * 16 + q * 4;
        #pragma unroll
        for (int i = 0; i < 4; ++i) {
            int r = rbase + i;
            if (r < N) {
                float dv = dinv[r];
                #pragma unroll
                for (int nt = 0; nt < 4; ++nt)
                    h1b[(long)r * 64 + nt * 16 + l16] = (__bf16)(acc[mt][nt][i] * dv);
            }
        }
    }
}

// ------- gather1 + gemm2 fused (fat-gather over CSR): lane = (slot g, chunk c).
// Each lane gathers 16 B (bf16x8); 8 lanes cover a 128-B h1b row; 4 rows in
// flight per iteration; NO shuffles in the inner loop. N % 4 == 0.

__global__ __launch_bounds__(256) void gather1_gemm2_kernel(
    const int* __restrict__ rowptr, const int* __restrict__ cnt,
    const int* __restrict__ adj,
    const float* __restrict__ dinv, const __bf16* __restrict__ h1b,
    const float* __restrict__ b1, const float* __restrict__ W2,
    __bf16* __restrict__ h2b, int N) {
    __shared__ float w2s[H_DIM][C_DIM];     // 8 KB
    __shared__ float b1s[64];
    __shared__ float r1s[4][64];            // per-wave relu(out1) row
    for (int i = threadIdx.x; i < H_DIM * C_DIM; i += 256)
        w2s[i / C_DIM][i % C_DIM] = W2[i];
    if (threadIdx.x < 64)
        b1s[threadIdx.x] = (threadIdx.x < H_DIM) ? b1[threadIdx.x] : 0.0f;
    __syncthreads();

    const int lane = threadIdx.x & 63;
    const int wv = threadIdx.x >> 6;
    const int n = blockIdx.x * 4 + wv;      // N % 4 == 0: always valid
    const int c = lane & 7;                 // col-chunk (8 bf16 = 16 B)
    const int g = lane >> 3;                // neighbor-slot 0..7

    float acc[8];
    #pragma unroll
    for (int i = 0; i < 8; ++i) acc[i] = 0.0f;

    if (g == 0) {                           // self-loop row, counted once
        bf16x8 v = *(const bf16x8*)(h1b + (long)n * 64 + c * 8);
        #pragma unroll
        for (int i = 0; i < 8; ++i) acc[i] += (float)v[i];
    }

    const int c0 = cnt[n];
    const int* row = adj + rowptr[n];
    for (int base = 0; base < c0; base += 32) {
        int j0 = base + g, j1 = j0 + 8, j2 = j0 + 16, j3 = j0 + 24;
        bool p0 = j0 < c0, p1 = j1 < c0, p2 = j2 < c0, p3 = j3 < c0;
        int i0 = p0 ? row[j0] : n;          // clamp to valid addr, mask the add
        int i1 = p1 ? row[j1] : n;
        int i2 = p2 ? row[j2] : n;
        int i3 = p3 ? row[j3] : n;
        bf16x8 v0 = *(const bf16x8*)(h1b + (long)i0 * 64 + c * 8);
        bf16x8 v1 = *(const bf16x8*)(h1b + (long)i1 * 64 + c * 8);
        bf16x8 v2 = *(const bf16x8*)(h1b + (long)i2 * 64 + c * 8);
        bf16x8 v3 = *(const bf16x8*)(h1b + (long)i3 * 64 + c * 8);
        float m0 = p0 ? 1.f : 0.f, m1 = p1 ? 1.f : 0.f;
        float m2 = p2 ? 1.f : 0.f, m3 = p3 ? 1.f : 0.f;
        #pragma unroll
        for (int i = 0; i < 8; ++i) {
            acc[i] = fmaf(m0, (float)v0[i], acc[i]);
            acc[i] = fmaf(m1, (float)v1[i], acc[i]);
            acc[i] = fmaf(m2, (float)v2[i], acc[i]);
            acc[i] = fmaf(m3, (float)v3[i], acc[i]);
        }
    }

    #pragma unroll
    for (int i = 0; i < 8; ++i) {           // reduce across neighbor-slots
        acc[i] += __shfl_xor(acc[i], 8, 64);
        acc[i] += __shfl_xor(acc[i], 16, 64);
        acc[i] += __shfl_xor(acc[i], 32, 64);
    }
    const float dv = dinv[n];
    if (g == 0) {                           // lanes 0..7 hold chunks 0..7
        #pragma unroll
        for (int i = 0; i < 8; ++i)
            r1s[wv][c * 8 + i] = fmaxf(acc[i] * dv + b1s[c * 8 + i], 0.0f);
    }
    __syncthreads();                        // all 256 threads reach here

    float h2 = 0.0f;
    if (lane < C_DIM) {
        float a2 = 0.0f;
        #pragma unroll
        for (int k = 0; k < H_DIM; ++k) a2 += r1s[wv][k] * w2s[k][lane];
        h2 = a2 * dv;
    }
    h2b[(long)n * 64 + lane] = (lane < C_DIM) ? (__bf16)h2 : (__bf16)0.0f;
}

// ------- gather2 + log_softmax (same fat-gather structure over CSR) -------------

__global__ __launch_bounds__(256) void gather2_kernel(
    const int* __restrict__ rowptr, const int* __restrict__ cnt,
    const int* __restrict__ adj,
    const float* __restrict__ dinv, const __bf16* __restrict__ h2b,
    const float* __restrict__ b2, float* __restrict__ out2, int N) {
    __shared__ float sc[4][64];
    const int lane = threadIdx.x & 63;
    const int wv = threadIdx.x >> 6;
    const int n = blockIdx.x * 4 + wv;      // N % 4 == 0: always valid
    const int c = lane & 7;
    const int g = lane >> 3;

    float acc[8];
    #pragma unroll
    for (int i = 0; i < 8; ++i) acc[i] = 0.0f;

    if (g == 0) {                           // self-loop row
        bf16x8 v = *(const bf16x8*)(h2b + (long)n * 64 + c * 8);
        #pragma unroll
        for (int i = 0; i < 8; ++i) acc[i] += (float)v[i];
    }

    const int c0 = cnt[n];
    const int* row = adj + rowptr[n];
    for (int base = 0; base < c0; base += 32) {
        int j0 = base + g, j1 = j0 + 8, j2 = j0 + 16, j3 = j0 + 24;
        bool p0 = j0 < c0, p1 = j1 < c0, p2 = j2 < c0, p3 = j3 < c0;
        int i0 = p0 ? row[j0] : n;
        int i1 = p1 ? row[j1] : n;
        int i2 = p2 ? row[j2] : n;
        int i3 = p3 ? row[j3] : n;
        bf16x8 v0 = *(const bf16x8*)(h2b + (long)i0 * 64 + c * 8);
        bf16x8 v1 = *(const bf16x8*)(h2b + (long)i1 * 64 + c * 8);
        bf16x8 v2 = *(const bf16x8*)(h2b + (long)i2 * 64 + c * 8);
        bf16x8 v3 = *(const bf16x8*)(h2b + (long)i3 * 64 + c * 8);
        float m0 = p0 ? 1.f : 0.f, m1 = p1 ? 1.f : 0.f;
        float m2 = p2 ? 1.f : 0.f, m3 = p3 ? 1.f : 0.f;
        #pragma unroll
        for (int i = 0; i < 8; ++i) {
            acc[i] = fmaf(m0, (float)v0[i], acc[i]);
            acc[i] = fmaf(m1, (float)v1[i], acc[i]);
            acc[i] = fmaf(m2, (float)v2[i], acc[i]);
            acc[i] = fmaf(m3, (float)v3[i], acc[i]);
        }
    }

    #pragma unroll
    for (int i = 0; i < 8; ++i) {
        acc[i] += __shfl_xor(acc[i], 8, 64);
        acc[i] += __shfl_xor(acc[i], 16, 64);
        acc[i] += __shfl_xor(acc[i], 32, 64);
    }
    if (g == 0) {
        #pragma unroll
        for (int i = 0; i < 8; ++i) sc[wv][c * 8 + i] = acc[i];
    }
    __syncthreads();                        // restore lane=col layout

    const bool valid = lane < C_DIM;
    float v = valid ? (sc[wv][lane] * dinv[n] + b2[lane]) : -INFINITY;

    float m = v;
    #pragma unroll
    for (int off = 1; off < 64; off <<= 1)
        m = fmaxf(m, __shfl_xor(m, off, 64));
    float ex = valid ? __expf(v - m) : 0.0f;
    #pragma unroll
    for (int off = 1; off < 64; off <<= 1)
        ex += __shfl_xor(ex, off, 64);
    float ls = __logf(ex) + m;
    if (valid) out2[(long)n * C_DIM + lane] = v - ls;
}

// ---------------- launch ----------------

extern "C" void kernel_launch(void* const* d_in, const int* in_sizes, int n_in,
                              void* d_out, int out_size, void* d_ws, size_t ws_size,
                              hipStream_t stream) {
    const float* x  = (const float*)d_in[0];
    const float* W1 = (const float*)d_in[1];
    const float* b1 = (const float*)d_in[2];
    const float* W2 = (const float*)d_in[3];
    const float* b2 = (const float*)d_in[4];
    const int* ei   = (const int*)d_in[5];

    const int N = in_sizes[0] / F_IN;   // 100000
    const int E = in_sizes[5] / 2;      // 3200000
    const int* src = ei;
    const int* dst = ei + E;
    float* out2 = (float*)d_out;

    // ws layout (4B words):
    // cnt[N] | rowptr[N] | cursor[N] | blksum[1024] | adj[E] | dinv[N] | wt | h1b | h2b
    int* wsw = (int*)d_ws;
    long o = 0;
    int*    cnt    = wsw + o;  o += N;
    int*    rowptr = wsw + o;  o += N;
    int*    cursor = wsw + o;  o += N;
    int*    blksum = wsw + o;  o += 1024;
    int*    adj    = wsw + o;  o += E;
    float*  dinv   = (float*)(wsw + o); o += N;
    __bf16* wt     = (__bf16*)(wsw + o); o += (64 * 512) / 2;
    __bf16* h1b    = (__bf16*)(wsw + o); o += (long)N * 32;
    __bf16* h2b    = (__bf16*)(wsw + o); o += (long)N * 32;

    const int BT = 256;
    const int gN   = (N + BT - 1) / BT;        // 391
    const int gE4  = (E / 4 + BT - 1) / BT;    // 3125
    const int gS   = (N + 1023) / 1024;        // 98 scan blocks

    zero_int_kernel<<<gN, BT, 0, stream>>>(cnt, N);
    count_kernel<<<gE4, BT, 0, stream>>>(dst, cnt, E);
    scan1_kernel<<<gS, BT, 0, stream>>>(cnt, rowptr, blksum, N);
    scan2_kernel<<<1, 64, 0, stream>>>(blksum, gS);
    scan3_kernel<<<gS, BT, 0, stream>>>(rowptr, blksum, cursor, cnt, dinv, N);
    csr_fill_kernel<<<gE4, BT, 0, stream>>>(src, dst, cursor, adj, E);
    prep_wt_kernel<<<128, 256, 0, stream>>>(W1, wt);

    gemm1_mfma_kernel<<<(N + G1_BM - 1) / G1_BM, 256, 0, stream>>>(x, wt, dinv, h1b, N);
    gather1_gemm2_kernel<<<N / 4, 256, 0, stream>>>(rowptr, cnt, adj, dinv, h1b, b1, W2, h2b, N);
    gather2_kernel<<<N / 4, 256, 0, stream>>>(rowptr, cnt, adj, dinv, h2b, b2, out2, N);
}

// Round 5
// 818.102 us; speedup vs baseline: 1.0597x; 1.0597x over previous
//
#include <hip/hip_runtime.h>
#include <hip/hip_bf16.h>
#include <math.h>

#define F_IN 512
#define H_DIM 50
#define C_DIM 40
#define NB_SHIFT 12   // bucket = dst >> 12 -> 25 buckets for N=100000 (<=32)

typedef __bf16 bf16x8 __attribute__((ext_vector_type(8)));
typedef __bf16 bf16x4 __attribute__((ext_vector_type(4)));
typedef float f32x4 __attribute__((ext_vector_type(4)));

// ---------------- CSR build via bucket partition --------------------------------
// csr_fill's 280us came from 15x write amplification (WRITE_SIZE 195MB for a
// 12.8MB adj): random 4-B scatter over a 12.8-MB window with all blocks resident
// evicts partially-written lines from every XCD L2. Fix: partition edges into
// 25 dst-buckets (append-only full-line writes), then scatter bucket-by-bucket
// with an XCD-contiguous chunk swizzle so each XCD's write window ~1.6MB << L2.

__global__ void zero_int_kernel(int* __restrict__ p, int n) {
    int i = blockIdx.x * blockDim.x + threadIdx.x;
    if (i < n) p[i] = 0;
}

__global__ __launch_bounds__(256) void bhist_kernel(const int* __restrict__ dst,
                                                    int* __restrict__ bcnt, int E) {
    __shared__ int hb[32];
    if (threadIdx.x < 32) hb[threadIdx.x] = 0;
    __syncthreads();
    int e0 = (blockIdx.x * 256 + threadIdx.x) * 4;
    if (e0 + 3 < E) {
        int4 d4 = *(const int4*)(dst + e0);
        atomicAdd(&hb[d4.x >> NB_SHIFT], 1);
        atomicAdd(&hb[d4.y >> NB_SHIFT], 1);
        atomicAdd(&hb[d4.z >> NB_SHIFT], 1);
        atomicAdd(&hb[d4.w >> NB_SHIFT], 1);
    } else if (e0 < E) {
        for (int j = 0; j < 4 && e0 + j < E; ++j)
            atomicAdd(&hb[dst[e0 + j] >> NB_SHIFT], 1);
    }
    __syncthreads();
    if (threadIdx.x < 32 && hb[threadIdx.x])
        atomicAdd(&bcnt[threadIdx.x], hb[threadIdx.x]);
}

__global__ void bscan_kernel(const int* __restrict__ bcnt, int* __restrict__ bcur, int nb) {
    if (threadIdx.x == 0) {
        int sum = 0;
        for (int i = 0; i < nb; ++i) { bcur[i] = sum; sum += bcnt[i]; }
    }
}

// partition: LDS-rank per bucket, one global reservation per block-bucket,
// append (src,dst) pairs in ~41-edge contiguous runs. Row-count atomics fused.
__global__ __launch_bounds__(256) void partition_kernel(
    const int* __restrict__ src, const int* __restrict__ dst,
    int* __restrict__ cnt, int* __restrict__ bcur,
    int2* __restrict__ ebuf, int E) {
    __shared__ int lcnt[32];
    __shared__ int lbase[32];
    const int t = threadIdx.x;
    if (t < 32) lcnt[t] = 0;
    __syncthreads();
    int e0 = (blockIdx.x * 256 + t) * 4;
    int s[4], d[4], bk[4], rk[4];
    int ne = 0;
    if (e0 + 3 < E) {
        int4 d4 = *(const int4*)(dst + e0);
        int4 s4 = *(const int4*)(src + e0);
        s[0] = s4.x; s[1] = s4.y; s[2] = s4.z; s[3] = s4.w;
        d[0] = d4.x; d[1] = d4.y; d[2] = d4.z; d[3] = d4.w;
        ne = 4;
    } else if (e0 < E) {
        for (; ne < 4 && e0 + ne < E; ++ne) { s[ne] = src[e0 + ne]; d[ne] = dst[e0 + ne]; }
    }
    #pragma unroll
    for (int j = 0; j < 4; ++j)
        if (j < ne) {
            bk[j] = d[j] >> NB_SHIFT;
            rk[j] = atomicAdd(&lcnt[bk[j]], 1);
            atomicAdd(&cnt[d[j]], 1);
        }
    __syncthreads();
    if (t < 32) lbase[t] = lcnt[t] ? atomicAdd(&bcur[t], lcnt[t]) : 0;
    __syncthreads();
    #pragma unroll
    for (int j = 0; j < 4; ++j)
        if (j < ne)
            ebuf[lbase[bk[j]] + rk[j]] = make_int2(s[j], d[j]);
}

// scan1: per-block (1024 elems) exclusive scan of cnt -> rowptr (local), blksum[b]
__global__ __launch_bounds__(256) void scan1_kernel(
    const int* __restrict__ cnt, int* __restrict__ rowptr,
    int* __restrict__ blksum, int N) {
    __shared__ int wsum[4];
    const int t = threadIdx.x, lane = t & 63, wv = t >> 6;
    const int base = blockIdx.x * 1024 + t * 4;
    int v[4];
    #pragma unroll
    for (int j = 0; j < 4; ++j) v[j] = (base + j < N) ? cnt[base + j] : 0;
    int tsum = v[0] + v[1] + v[2] + v[3];
    int incl = tsum;
    #pragma unroll
    for (int off = 1; off < 64; off <<= 1) {
        int u = __shfl_up(incl, off, 64);
        if (lane >= off) incl += u;
    }
    if (lane == 63) wsum[wv] = incl;
    __syncthreads();
    int woff = 0;
    #pragma unroll
    for (int w = 0; w < 3; ++w) woff += (w < wv) ? wsum[w] : 0;
    int e = woff + incl - tsum;     // exclusive prefix of this thread's first elem
    #pragma unroll
    for (int j = 0; j < 4; ++j) {
        if (base + j < N) rowptr[base + j] = e;
        e += v[j];
    }
    if (t == 255) blksum[blockIdx.x] = woff + incl;   // block total
}

// scan2: exclusive scan of block sums in place (1 block, 64 threads)
__global__ void scan2_kernel(int* __restrict__ blksum, int nb) {
    const int lane = threadIdx.x;
    int run = 0;
    for (int base = 0; base < nb; base += 64) {
        int v = (base + lane < nb) ? blksum[base + lane] : 0;
        int incl = v;
        #pragma unroll
        for (int off = 1; off < 64; off <<= 1) {
            int u = __shfl_up(incl, off, 64);
            if (lane >= off) incl += u;
        }
        if (base + lane < nb) blksum[base + lane] = run + incl - v;
        run += __shfl(incl, 63, 64);
    }
}

// scan3: add block offsets, init cursor, compute dinv (fused small pass)
__global__ __launch_bounds__(256) void scan3_kernel(
    int* __restrict__ rowptr, const int* __restrict__ blksum,
    int* __restrict__ cursor, const int* __restrict__ cnt,
    float* __restrict__ dinv, int N) {
    const int base = blockIdx.x * 1024 + threadIdx.x * 4;
    const int off = blksum[blockIdx.x];
    #pragma unroll
    for (int j = 0; j < 4; ++j) {
        int i = base + j;
        if (i < N) {
            int r = rowptr[i] + off;
            rowptr[i] = r;
            cursor[i] = r;
            dinv[i] = rsqrtf((float)(cnt[i] + 1));   // +1 self-loop
        }
    }
}

// scatter: consume bucketed ebuf with XCD-contiguous chunk swizzle (m204
// bijective). xcd = bid&7 owns a contiguous 1/8 of ebuf -> adj write window
// ~1.6 MB per XCD, fits 4 MB L2 -> writes merge before eviction.
__global__ __launch_bounds__(256) void scatter_kernel(
    const int2* __restrict__ ebuf, int* __restrict__ cursor,
    int* __restrict__ adj, int E, int nblk) {
    int q = nblk >> 3, r = nblk & 7;
    int x = blockIdx.x & 7, sq = blockIdx.x >> 3;
    int blk = (x < r) ? x * (q + 1) + sq : r * (q + 1) + (x - r) * q + sq;
    int e0 = (blk * 256 + threadIdx.x) * 4;
    if (e0 >= E) return;
    if (e0 + 3 < E) {
        int4 a = *(const int4*)(ebuf + e0);       // edges e0, e0+1
        int4 b = *(const int4*)(ebuf + e0 + 2);   // edges e0+2, e0+3
        int p0 = atomicAdd(&cursor[a.y], 1); adj[p0] = a.x;
        int p1 = atomicAdd(&cursor[a.w], 1); adj[p1] = a.z;
        int p2 = atomicAdd(&cursor[b.y], 1); adj[p2] = b.x;
        int p3 = atomicAdd(&cursor[b.w], 1); adj[p3] = b.z;
    } else {
        for (int j = 0; j < 4 && e0 + j < E; ++j) {
            int2 e = ebuf[e0 + j];
            int p = atomicAdd(&cursor[e.y], 1); adj[p] = e.x;
        }
    }
}

// ---------------- W1 -> bf16 transposed [64][512] (cols>=50 zero) ----------------

__global__ void prep_wt_kernel(const float* __restrict__ W1, __bf16* __restrict__ wt) {
    int i = blockIdx.x * 256 + threadIdx.x;   // 0..32767
    int n = i >> 9, k = i & 511;
    wt[n * 512 + k] = (n < H_DIM) ? (__bf16)W1[k * H_DIM + n] : (__bf16)0.0f;
}

// ---------------- GEMM1 (MFMA): h1b = bf16( (x @ W1) * dinv[row] ), [N][64] ------
// 128x64 tile, BK=32, 4 waves, double-buffered.
// LDS rows padded to 80 B (40 bf16): frag-read bank-unit = (5*row + q) mod 8 is
// uniform 8 lanes/unit -> conflict-free. 30 KB LDS -> 5 blocks/CU = 62.5% occ.

#define G1_BM 128
#define G1_BK 32
#define A_LDW 40   // padded row stride in bf16 (80 B)

__device__ __forceinline__ bf16x4 pack4(float4 a) {
    bf16x4 r;
    r[0] = (__bf16)a.x; r[1] = (__bf16)a.y; r[2] = (__bf16)a.z; r[3] = (__bf16)a.w;
    return r;
}

__global__ __launch_bounds__(256) void gemm1_mfma_kernel(
    const float* __restrict__ x, const __bf16* __restrict__ wt,
    const float* __restrict__ dinv, __bf16* __restrict__ h1b, int N) {
    __shared__ __bf16 As[2][G1_BM * A_LDW];   // 2 x 10 KB
    __shared__ __bf16 Bs[2][64 * A_LDW];      // 2 x 5 KB

    const int t = threadIdx.x;
    const int wv = t >> 6, ln = t & 63;
    const int q = ln >> 4, l16 = ln & 15;
    const int row0 = blockIdx.x * G1_BM;

    f32x4 acc[2][4];
    #pragma unroll
    for (int a = 0; a < 2; ++a)
        #pragma unroll
        for (int b = 0; b < 4; ++b) acc[a][b] = (f32x4){0.f, 0.f, 0.f, 0.f};

    // A staging: thread owns float4-slot c4 (16 B) of rows r0+32j.
    const int c4 = t & 7;
    const int r0 = t >> 3;          // 0..31
    const float* xp[4];
    #pragma unroll
    for (int j = 0; j < 4; ++j) {
        int gr = row0 + r0 + 32 * j;
        int rc = (gr < N) ? gr : (N - 1);   // clamp: junk A-rows -> discarded C-rows
        xp[j] = x + (long)rc * F_IN + c4 * 4;
    }

    // B staging: thread owns bf16x8 chunk bc of row bn.
    const int bc = t & 3;
    const int bn = t >> 2;          // 0..63
    const __bf16* wb = wt + bn * 512 + bc * 8;

    float4 xv[4];
    uint4 w8;

    #pragma unroll
    for (int j = 0; j < 4; ++j) xv[j] = *(const float4*)(xp[j]);
    w8 = *(const uint4*)(wb);
    #pragma unroll
    for (int j = 0; j < 4; ++j)
        *(bf16x4*)&As[0][(r0 + 32 * j) * A_LDW + c4 * 4] = pack4(xv[j]);
    *(bf16x8*)&Bs[0][bn * A_LDW + bc * 8] = *(bf16x8*)&w8;
    __syncthreads();

    #pragma unroll 1
    for (int tt = 0; tt < F_IN / G1_BK; ++tt) {
        int b = tt & 1;
        if (tt < F_IN / G1_BK - 1) {
            #pragma unroll
            for (int j = 0; j < 4; ++j)
                xv[j] = *(const float4*)(xp[j] + (tt + 1) * G1_BK);
            w8 = *(const uint4*)(wb + (tt + 1) * G1_BK);
        }
        bf16x8 af[2], bfr[4];
        #pragma unroll
        for (int mt = 0; mt < 2; ++mt)
            af[mt] = *(const bf16x8*)&As[b][(wv * 32 + mt * 16 + l16) * A_LDW + q * 8];
        #pragma unroll
        for (int nt = 0; nt < 4; ++nt)
            bfr[nt] = *(const bf16x8*)&Bs[b][(nt * 16 + l16) * A_LDW + q * 8];
        #pragma unroll
        for (int mt = 0; mt < 2; ++mt)
            #pragma unroll
            for (int nt = 0; nt < 4; ++nt)
                acc[mt][nt] = __builtin_amdgcn_mfma_f32_16x16x32_bf16(
                    af[mt], bfr[nt], acc[mt][nt], 0, 0, 0);
        if (tt < F_IN / G1_BK - 1) {
            int nb = b ^ 1;
            #pragma unroll
            for (int j = 0; j < 4; ++j)
                *(bf16x4*)&As[nb][(r0 + 32 * j) * A_LDW + c4 * 4] = pack4(xv[j]);
            *(bf16x8*)&Bs[nb][bn * A_LDW + bc * 8] = *(bf16x8*)&w8;
        }
        __syncthreads();
    }

    #pragma unroll
    for (int mt = 0; mt < 2; ++mt) {
        int rbase = row0 + wv * 32 + mt * 16 + q * 4;
        #pragma unroll
        for (int i = 0; i < 4; ++i) {
            int r = rbase + i;
            if (r < N) {
                float dv = dinv[r];
                #pragma unroll
                for (int nt = 0; nt < 4; ++nt)
                    h1b[(long)r * 64 + nt * 16 + l16] = (__bf16)(acc[mt][nt][i] * dv);
            }
        }
    }
}

// ------- gather1 + gemm2 fused (fat-gather over CSR): lane = (slot g, chunk c).
// Each lane gathers 16 B (bf16x8); 8 lanes cover a 128-B h1b row; 4 rows in
// flight per iteration; NO shuffles in the inner loop. N % 4 == 0.

__global__ __launch_bounds__(256) void gather1_gemm2_kernel(
    const int* __restrict__ rowptr, const int* __restrict__ cnt,
    const int* __restrict__ adj,
    const float* __restrict__ dinv, const __bf16* __restrict__ h1b,
    const float* __restrict__ b1, const float* __restrict__ W2,
    __bf16* __restrict__ h2b, int N) {
    __shared__ float w2s[H_DIM][C_DIM];     // 8 KB
    __shared__ float b1s[64];
    __shared__ float r1s[4][64];            // per-wave relu(out1) row
    for (int i = threadIdx.x; i < H_DIM * C_DIM; i += 256)
        w2s[i / C_DIM][i % C_DIM] = W2[i];
    if (threadIdx.x < 64)
        b1s[threadIdx.x] = (threadIdx.x < H_DIM) ? b1[threadIdx.x] : 0.0f;
    __syncthreads();

    const int lane = threadIdx.x & 63;
    const int wv = threadIdx.x >> 6;
    const int n = blockIdx.x * 4 + wv;      // N % 4 == 0: always valid
    const int c = lane & 7;                 // col-chunk (8 bf16 = 16 B)
    const int g = lane >> 3;                // neighbor-slot 0..7

    float acc[8];
    #pragma unroll
    for (int i = 0; i < 8; ++i) acc[i] = 0.0f;

    if (g == 0) {                           // self-loop row, counted once
        bf16x8 v = *(const bf16x8*)(h1b + (long)n * 64 + c * 8);
        #pragma unroll
        for (int i = 0; i < 8; ++i) acc[i] += (float)v[i];
    }

    const int c0 = cnt[n];
    const int* row = adj + rowptr[n];
    for (int base = 0; base < c0; base += 32) {
        int j0 = base + g, j1 = j0 + 8, j2 = j0 + 16, j3 = j0 + 24;
        bool p0 = j0 < c0, p1 = j1 < c0, p2 = j2 < c0, p3 = j3 < c0;
        int i0 = p0 ? row[j0] : n;          // clamp to valid addr, mask the add
        int i1 = p1 ? row[j1] : n;
        int i2 = p2 ? row[j2] : n;
        int i3 = p3 ? row[j3] : n;
        bf16x8 v0 = *(const bf16x8*)(h1b + (long)i0 * 64 + c * 8);
        bf16x8 v1 = *(const bf16x8*)(h1b + (long)i1 * 64 + c * 8);
        bf16x8 v2 = *(const bf16x8*)(h1b + (long)i2 * 64 + c * 8);
        bf16x8 v3 = *(const bf16x8*)(h1b + (long)i3 * 64 + c * 8);
        float m0 = p0 ? 1.f : 0.f, m1 = p1 ? 1.f : 0.f;
        float m2 = p2 ? 1.f : 0.f, m3 = p3 ? 1.f : 0.f;
        #pragma unroll
        for (int i = 0; i < 8; ++i) {
            acc[i] = fmaf(m0, (float)v0[i], acc[i]);
            acc[i] = fmaf(m1, (float)v1[i], acc[i]);
            acc[i] = fmaf(m2, (float)v2[i], acc[i]);
            acc[i] = fmaf(m3, (float)v3[i], acc[i]);
        }
    }

    #pragma unroll
    for (int i = 0; i < 8; ++i) {           // reduce across neighbor-slots
        acc[i] += __shfl_xor(acc[i], 8, 64);
        acc[i] += __shfl_xor(acc[i], 16, 64);
        acc[i] += __shfl_xor(acc[i], 32, 64);
    }
    const float dv = dinv[n];
    if (g == 0) {                           // lanes 0..7 hold chunks 0..7
        #pragma unroll
        for (int i = 0; i < 8; ++i)
            r1s[wv][c * 8 + i] = fmaxf(acc[i] * dv + b1s[c * 8 + i], 0.0f);
    }
    __syncthreads();                        // all 256 threads reach here

    float h2 = 0.0f;
    if (lane < C_DIM) {
        float a2 = 0.0f;
        #pragma unroll
        for (int k = 0; k < H_DIM; ++k) a2 += r1s[wv][k] * w2s[k][lane];
        h2 = a2 * dv;
    }
    h2b[(long)n * 64 + lane] = (lane < C_DIM) ? (__bf16)h2 : (__bf16)0.0f;
}

// ------- gather2 + log_softmax (same fat-gather structure over CSR) -------------

__global__ __launch_bounds__(256) void gather2_kernel(
    const int* __restrict__ rowptr, const int* __restrict__ cnt,
    const int* __restrict__ adj,
    const float* __restrict__ dinv, const __bf16* __restrict__ h2b,
    const float* __restrict__ b2, float* __restrict__ out2, int N) {
    __shared__ float sc[4][64];
    const int lane = threadIdx.x & 63;
    const int wv = threadIdx.x >> 6;
    const int n = blockIdx.x * 4 + wv;      // N % 4 == 0: always valid
    const int c = lane & 7;
    const int g = lane >> 3;

    float acc[8];
    #pragma unroll
    for (int i = 0; i < 8; ++i) acc[i] = 0.0f;

    if (g == 0) {                           // self-loop row
        bf16x8 v = *(const bf16x8*)(h2b + (long)n * 64 + c * 8);
        #pragma unroll
        for (int i = 0; i < 8; ++i) acc[i] += (float)v[i];
    }

    const int c0 = cnt[n];
    const int* row = adj + rowptr[n];
    for (int base = 0; base < c0; base += 32) {
        int j0 = base + g, j1 = j0 + 8, j2 = j0 + 16, j3 = j0 + 24;
        bool p0 = j0 < c0, p1 = j1 < c0, p2 = j2 < c0, p3 = j3 < c0;
        int i0 = p0 ? row[j0] : n;
        int i1 = p1 ? row[j1] : n;
        int i2 = p2 ? row[j2] : n;
        int i3 = p3 ? row[j3] : n;
        bf16x8 v0 = *(const bf16x8*)(h2b + (long)i0 * 64 + c * 8);
        bf16x8 v1 = *(const bf16x8*)(h2b + (long)i1 * 64 + c * 8);
        bf16x8 v2 = *(const bf16x8*)(h2b + (long)i2 * 64 + c * 8);
        bf16x8 v3 = *(const bf16x8*)(h2b + (long)i3 * 64 + c * 8);
        float m0 = p0 ? 1.f : 0.f, m1 = p1 ? 1.f : 0.f;
        float m2 = p2 ? 1.f : 0.f, m3 = p3 ? 1.f : 0.f;
        #pragma unroll
        for (int i = 0; i < 8; ++i) {
            acc[i] = fmaf(m0, (float)v0[i], acc[i]);
            acc[i] = fmaf(m1, (float)v1[i], acc[i]);
            acc[i] = fmaf(m2, (float)v2[i], acc[i]);
            acc[i] = fmaf(m3, (float)v3[i], acc[i]);
        }
    }

    #pragma unroll
    for (int i = 0; i < 8; ++i) {
        acc[i] += __shfl_xor(acc[i], 8, 64);
        acc[i] += __shfl_xor(acc[i], 16, 64);
        acc[i] += __shfl_xor(acc[i], 32, 64);
    }
    if (g == 0) {
        #pragma unroll
        for (int i = 0; i < 8; ++i) sc[wv][c * 8 + i] = acc[i];
    }
    __syncthreads();                        // restore lane=col layout

    const bool valid = lane < C_DIM;
    float v = valid ? (sc[wv][lane] * dinv[n] + b2[lane]) : -INFINITY;

    float m = v;
    #pragma unroll
    for (int off = 1; off < 64; off <<= 1)
        m = fmaxf(m, __shfl_xor(m, off, 64));
    float ex = valid ? __expf(v - m) : 0.0f;
    #pragma unroll
    for (int off = 1; off < 64; off <<= 1)
        ex += __shfl_xor(ex, off, 64);
    float ls = __logf(ex) + m;
    if (valid) out2[(long)n * C_DIM + lane] = v - ls;
}

// ---------------- launch ----------------

extern "C" void kernel_launch(void* const* d_in, const int* in_sizes, int n_in,
                              void* d_out, int out_size, void* d_ws, size_t ws_size,
                              hipStream_t stream) {
    const float* x  = (const float*)d_in[0];
    const float* W1 = (const float*)d_in[1];
    const float* b1 = (const float*)d_in[2];
    const float* W2 = (const float*)d_in[3];
    const float* b2 = (const float*)d_in[4];
    const int* ei   = (const int*)d_in[5];

    const int N = in_sizes[0] / F_IN;   // 100000
    const int E = in_sizes[5] / 2;      // 3200000
    const int* src = ei;
    const int* dst = ei + E;
    float* out2 = (float*)d_out;

    // ws layout (4B words): cnt[N] | bcnt[32] | bcur[32] | rowptr[N] | cursor[N] |
    //   blksum[1024] | adj[E] | ebuf[2E] | dinv[N] | wt | h1b | h2b
    int* wsw = (int*)d_ws;
    long o = 0;
    int*    cnt    = wsw + o;  o += N;
    int*    bcnt   = wsw + o;  o += 32;
    int*    bcur   = wsw + o;  o += 32;
    int*    rowptr = wsw + o;  o += N;
    int*    cursor = wsw + o;  o += N;
    int*    blksum = wsw + o;  o += 1024;
    int*    adj    = wsw + o;  o += E;
    int2*   ebuf   = (int2*)(wsw + o); o += (long)E * 2;
    float*  dinv   = (float*)(wsw + o); o += N;
    __bf16* wt     = (__bf16*)(wsw + o); o += (64 * 512) / 2;
    __bf16* h1b    = (__bf16*)(wsw + o); o += (long)N * 32;
    __bf16* h2b    = (__bf16*)(wsw + o); o += (long)N * 32;

    const int BT = 256;
    const int gE4  = (E / 4 + BT - 1) / BT;    // 3125
    const int gS   = (N + 1023) / 1024;        // 98 scan blocks
    const int nb   = (N + (1 << NB_SHIFT) - 1) >> NB_SHIFT;   // 25 buckets

    zero_int_kernel<<<(N + 64 + BT - 1) / BT, BT, 0, stream>>>(cnt, N + 64);  // cnt+bcnt+bcur
    bhist_kernel<<<gE4, BT, 0, stream>>>(dst, bcnt, E);
    bscan_kernel<<<1, 64, 0, stream>>>(bcnt, bcur, nb);
    partition_kernel<<<gE4, BT, 0, stream>>>(src, dst, cnt, bcur, ebuf, E);
    scan1_kernel<<<gS, BT, 0, stream>>>(cnt, rowptr, blksum, N);
    scan2_kernel<<<1, 64, 0, stream>>>(blksum, gS);
    scan3_kernel<<<gS, BT, 0, stream>>>(rowptr, blksum, cursor, cnt, dinv, N);
    scatter_kernel<<<gE4, BT, 0, stream>>>(ebuf, cursor, adj, E, gE4);
    prep_wt_kernel<<<128, 256, 0, stream>>>(W1, wt);

    gemm1_mfma_kernel<<<(N + G1_BM - 1) / G1_BM, 256, 0, stream>>>(x, wt, dinv, h1b, N);
    gather1_gemm2_kernel<<<N / 4, 256, 0, stream>>>(rowptr, cnt, adj, dinv, h1b, b1, W2, h2b, N);
    gather2_kernel<<<N / 4, 256, 0, stream>>>(rowptr, cnt, adj, dinv, h2b, b2, out2, N);
}